// Round 10
// baseline (332.754 us; speedup 1.0000x reference)
//
#include <hip/hip_runtime.h>
#include <hip/hip_bf16.h>
#include <math.h>

typedef __attribute__((ext_vector_type(8))) short bf16x8;
typedef __attribute__((ext_vector_type(4))) float f32x4;

#define HH 512
#define WW 512
#define CC 32

__device__ __forceinline__ unsigned short f2bf(float f) {
    unsigned u = __float_as_uint(f);
    u = (u + 0x7fffu + ((u >> 16) & 1u)) >> 16;
    return (unsigned short)u;
}

// One-shot weight prepack: wconv [co:32][ci:32][3][3] f32 -> wbuf u16 [t:9][h:4][co:32][e:8]
__global__ __launch_bounds__(256) void prepack(const float* __restrict__ wconv,
                                               unsigned short* __restrict__ wbuf) {
    int e = blockIdx.x * 256 + threadIdx.x;
    if (e < 9216) {
        int co  = e / 288;
        int rem = e - co * 288;
        int ci  = rem / 9;
        int t   = rem - ci * 9;
        wbuf[((t * 4 + (ci >> 3)) * 32 + co) * 8 + (ci & 7)] = f2bf(wconv[e]);
    }
}

// NCHW f32 -> NHWC bf16 transpose (streaming, LDS-tiled). Block = (b, y, 128-px slice).
__global__ __launch_bounds__(256) void to_nhwc(const float* __restrict__ cen,
                                               unsigned short* __restrict__ nhwc) {
    __shared__ float xs[32 * 132];
    const int tid = threadIdx.x;
    const int b  = blockIdx.z;
    const int y  = blockIdx.y;
    const int x0 = blockIdx.x << 7;

    // read phase: 32 ch x 32 quads, coalesced f32x4
#pragma unroll
    for (int it = 0; it < 4; ++it) {
        int e  = tid + (it << 8);
        int ch = e >> 5;
        int q  = e & 31;
        f32x4 v = *(const f32x4*)&cen[(((long)(b * CC + ch) * HH + y) * WW) + x0 + 4 * q];
        *(f32x4*)&xs[ch * 132 + 4 * q] = v;
    }
    __syncthreads();

    // write phase: 128 px x 4 chunks of 8 ch, coalesced 16B stores
#pragma unroll
    for (int it = 0; it < 2; ++it) {
        int e  = tid + (it << 8);
        int px = e >> 2;
        int k  = e & 3;
        unsigned short o[8];
#pragma unroll
        for (int i = 0; i < 8; ++i)
            o[i] = f2bf(xs[(8 * k + i) * 132 + px]);
        *(bf16x8*)&nhwc[(((long)(b * HH) + y) * WW + x0 + px) * 32 + 8 * k] = *(bf16x8*)o;
    }
}

// Kernel A: fused conv3x3(C32->C32, SAME) + BN(eval) + SiLU + conv1x1(C32->1)
// Implicit GEMM; input pre-converted to NHWC bf16 -> staging is pure 16B copy.
__global__ __launch_bounds__(256) void conv_fused(
    const unsigned short* __restrict__ nhwc, const unsigned short* __restrict__ wbuf,
    const float* __restrict__ gamma, const float* __restrict__ beta,
    const float* __restrict__ mean, const float* __restrict__ var,
    const float* __restrict__ w1x1, const float* __restrict__ b1x1,
    float* __restrict__ xout)
{
    // [sp = r*40 + px : 720][chunk:4][16B]; chunk XOR-swizzled by sp&3
    __shared__ unsigned short sIn[18 * 40 * 32];

    const int tid = threadIdx.x;
    const int b  = blockIdx.z;
    const int i0 = blockIdx.y << 4;
    const int j0 = blockIdx.x << 5;

    // ---- stage: 720 px x 4 chunks = 2880 16B tasks, OOB -> 0 ----
    for (int e = tid; e < 2880; e += 256) {
        int sp = e >> 2;
        int k  = e & 3;
        int r  = sp / 40;
        int px = sp - r * 40;
        int gy = i0 - 1 + r;
        int gx = j0 - 4 + px;
        bf16x8 v = {0, 0, 0, 0, 0, 0, 0, 0};
        if ((unsigned)gy < HH && (unsigned)gx < WW)
            v = *(const bf16x8*)&nhwc[(((long)(b * HH) + gy) * WW + gx) * 32 + 8 * k];
        *(bf16x8*)&sIn[sp * 32 + ((k ^ (sp & 3)) << 3)] = v;
    }

    const int lane = tid & 63;
    const int wv   = tid >> 6;
    const int l15  = lane & 15;
    const int h    = lane >> 4;

    // B fragments from global (identical across blocks -> L2)
    bf16x8 Bf[9][2];
#pragma unroll
    for (int t = 0; t < 9; ++t)
#pragma unroll
        for (int n = 0; n < 2; ++n)
            Bf[t][n] = *(const bf16x8*)&wbuf[((t * 4 + h) * 32 + n * 16 + l15) * 8];

    const float iv0 = gamma[l15]      / sqrtf(var[l15]      + 1e-5f);
    const float iv1 = gamma[l15 + 16] / sqrtf(var[l15 + 16] + 1e-5f);
    const float bb0 = beta[l15]      - mean[l15]      * iv0;
    const float bb1 = beta[l15 + 16] - mean[l15 + 16] * iv1;
    const float wa0 = w1x1[l15], wa1 = w1x1[l15 + 16];
    const float bias = b1x1[0];

    __syncthreads();

#pragma unroll
    for (int mt = 0; mt < 8; ++mt) {
        const int iloc = wv * 4 + (mt >> 1);
        const int jg   = mt & 1;
        const int xb   = jg * 16 + l15;
        f32x4 acc0 = {0.f, 0.f, 0.f, 0.f};
        f32x4 acc1 = {0.f, 0.f, 0.f, 0.f};
#pragma unroll
        for (int t = 0; t < 9; ++t) {
            const int sp = (iloc + t / 3) * 40 + xb + t % 3 + 3;
            bf16x8 A = *(const bf16x8*)&sIn[sp * 32 + ((h ^ (sp & 3)) << 3)];
            acc0 = __builtin_amdgcn_mfma_f32_16x16x32_bf16(A, Bf[t][0], acc0, 0, 0, 0);
            acc1 = __builtin_amdgcn_mfma_f32_16x16x32_bf16(A, Bf[t][1], acc1, 0, 0, 0);
        }
        float v[4];
#pragma unroll
        for (int r = 0; r < 4; ++r) {
            float y0 = acc0[r] * iv0 + bb0;
            float y1 = acc1[r] * iv1 + bb1;
            float s0 = y0 / (1.f + __expf(-y0));
            float s1 = y1 / (1.f + __expf(-y1));
            v[r] = wa0 * s0 + wa1 * s1;
        }
#pragma unroll
        for (int m = 1; m <= 8; m <<= 1) {
#pragma unroll
            for (int r = 0; r < 4; ++r)
                v[r] += __shfl_xor(v[r], m, 64);
        }
        if (l15 == 0) {
            const int i = i0 + iloc;
            const int j = j0 + jg * 16 + 4 * h;
            f32x4 o = {v[0] + bias, v[1] + bias, v[2] + bias, v[3] + bias};
            *(f32x4*)&xout[((long)b * HH + i) * WW + j] = o;
        }
    }
}

// att_compute: shifted-difference stencil on x -> att map [4][512][512] f32.
__global__ __launch_bounds__(256) void att_compute(
    const float* __restrict__ xin, float* __restrict__ attbuf)
{
    __shared__ float xs[8 * 520];
    const int tid = threadIdx.x;
    const int b   = blockIdx.x >> 8;
    const int ip  = blockIdx.x & 255;
    const int gy0 = 2 * ip - 3;
    const float* xp = xin + (long)b * HH * WW;

    for (int e = tid; e < 1040; e += 256) {
        int r  = e / 130;
        int q  = e - r * 130;
        int gy = gy0 + r;
        int gx0 = 4 * q - 4;
        f32x4 v = {0.f, 0.f, 0.f, 0.f};
        if ((unsigned)gy < HH && (unsigned)gx0 < (WW - 3))
            v = *(const f32x4*)&xp[gy * WW + gx0];
        *(f32x4*)&xs[r * 520 + 4 * q] = v;
    }
    __syncthreads();

    const int jq = tid & 127;
    const int il = tid >> 7;
    const int i  = 2 * ip + il;
    const int j  = jq << 2;

    float w3m[12], w1m[12], wc0[12], w1p[12], w3p[12];
#pragma unroll
    for (int k = 0; k < 3; ++k) {
        f32x4 a;
        a = *(const f32x4*)&xs[(il + 0) * 520 + 4 * (jq + k)];
        w3m[4*k] = a.x; w3m[4*k+1] = a.y; w3m[4*k+2] = a.z; w3m[4*k+3] = a.w;
        a = *(const f32x4*)&xs[(il + 2) * 520 + 4 * (jq + k)];
        w1m[4*k] = a.x; w1m[4*k+1] = a.y; w1m[4*k+2] = a.z; w1m[4*k+3] = a.w;
        a = *(const f32x4*)&xs[(il + 3) * 520 + 4 * (jq + k)];
        wc0[4*k] = a.x; wc0[4*k+1] = a.y; wc0[4*k+2] = a.z; wc0[4*k+3] = a.w;
        a = *(const f32x4*)&xs[(il + 4) * 520 + 4 * (jq + k)];
        w1p[4*k] = a.x; w1p[4*k+1] = a.y; w1p[4*k+2] = a.z; w1p[4*k+3] = a.w;
        a = *(const f32x4*)&xs[(il + 6) * 520 + 4 * (jq + k)];
        w3p[4*k] = a.x; w3p[4*k+1] = a.y; w3p[4*k+2] = a.z; w3p[4*k+3] = a.w;
    }

    f32x4 attv;
#pragma unroll
    for (int p = 0; p < 4; ++p) {
        const float c = wc0[p + 4];
        float d0 = (c - w1m[p + 3]) * (c - w1p[p + 5]);
        float d1 = (c - w1m[p + 4]) * (c - w1p[p + 4]);
        float d2 = (c - w1m[p + 5]) * (c - w1p[p + 3]);
        float d3 = (c - wc0[p + 3]) * (c - wc0[p + 5]);
        float o0 = fminf(fminf(d0, d1), fminf(d2, d3));
        d0 = (c - w3m[p + 1]) * (c - w3p[p + 7]);
        d1 = (c - w3m[p + 4]) * (c - w3p[p + 4]);
        d2 = (c - w3m[p + 7]) * (c - w3p[p + 1]);
        d3 = (c - wc0[p + 1]) * (c - wc0[p + 7]);
        float o1 = fminf(fminf(d0, d1), fminf(d2, d3));
        float a = 0.5f * (fmaxf(o0, o1) + 0.5f * (o0 + o1));
        a = a > 0.f ? a : 0.f;
        attv[p] = 1.f / (1.f + __expf(-a));
    }
    *(f32x4*)&attbuf[((long)b * HH + i) * WW + j] = attv;
}

// att_apply: out[n] = cen[n] * att[px(n)] — pure streaming, 8 indep quads/thread.
__global__ __launch_bounds__(256) void att_apply(
    const float* __restrict__ cen, const float* __restrict__ attbuf,
    float* __restrict__ out)
{
    const f32x4* cv = (const f32x4*)cen;
    const f32x4* av = (const f32x4*)attbuf;
    f32x4* ov = (f32x4*)out;
    const int t0 = blockIdx.x * 256 + threadIdx.x;   // 0 .. 2^20
#pragma unroll
    for (int it = 0; it < 8; ++it) {
        const int n = t0 + (it << 20);               // quad index, total 2^23
        const int aq = ((n >> 21) << 16) | (n & 65535);
        f32x4 a = av[aq];
        f32x4 c = cv[n];
        c.x *= a.x; c.y *= a.y; c.z *= a.z; c.w *= a.w;
        ov[n] = c;
    }
}

extern "C" void kernel_launch(void* const* d_in, const int* in_sizes, int n_in,
                              void* d_out, int out_size, void* d_ws, size_t ws_size,
                              hipStream_t stream) {
    const float* cen   = (const float*)d_in[0];
    const float* wconv = (const float*)d_in[1];
    const float* gamma = (const float*)d_in[2];
    const float* beta  = (const float*)d_in[3];
    const float* mean  = (const float*)d_in[4];
    const float* var   = (const float*)d_in[5];
    const float* w1x1  = (const float*)d_in[6];
    const float* b1x1  = (const float*)d_in[7];

    float* xbuf   = (float*)d_ws;                                    // [4][512][512] f32, 4 MB
    float* attbuf = (float*)((char*)d_ws + (4l << 20));              // [4][512][512] f32, 4 MB
    unsigned short* wbuf = (unsigned short*)((char*)d_ws + (8l << 20)); // 18 KB
    unsigned short* nhwc = (unsigned short*)d_out;                   // 64 MB scratch in d_out
    float* outp = (float*)d_out;

    prepack<<<dim3(36), 256, 0, stream>>>(wconv, wbuf);
    to_nhwc<<<dim3(4, 512, 4), 256, 0, stream>>>(cen, nhwc);
    conv_fused<<<dim3(16, 32, 4), 256, 0, stream>>>(
        nhwc, wbuf, gamma, beta, mean, var, w1x1, b1x1, xbuf);
    att_compute<<<dim3(1024), 256, 0, stream>>>(xbuf, attbuf);
    att_apply<<<dim3(4096), 256, 0, stream>>>(cen, attbuf, outp);
}